// Round 16
// baseline (574.892 us; speedup 1.0000x reference)
//
#include <hip/hip_runtime.h>

typedef float v2f __attribute__((ext_vector_type(2)));
typedef float v4f __attribute__((ext_vector_type(4)));

#define T_STEPS 2048
#define BATCH   2
#define IDIM    40
#define HDIM    44
#define GDIM    176      // 4*H
#define ADIM    262144
#define EDIM    88       // 2*H
#define NEG_L   (-1.4426950408889634f)   // -log2(e)
#define NEG_2L  (-2.8853900817779268f)   // -2*log2(e)
#define NACT_BLK 4096                    // action blocks (128 thr each)

// K1: xproj[t][b][gi] = scale(gi) * (b_ih[gi] + b_hh[gi] + x[t][b]·W_ih[gi])
__global__ __launch_bounds__(192) void xproj_kernel(
    const float* __restrict__ x,      // [T][B][40]
    const float* __restrict__ W_ih,   // [176][40]
    const float* __restrict__ b_ih,   // [176]
    const float* __restrict__ b_hh,   // [176]
    float* __restrict__ xproj)        // [T][B][176]
{
    const int tb = blockIdx.x;        // t*B + b
    const int gi = threadIdx.x;
    __shared__ __align__(16) float xs[IDIM];
    if (threadIdx.x < IDIM) xs[threadIdx.x] = x[(size_t)tb * IDIM + threadIdx.x];
    __syncthreads();
    if (gi < GDIM) {
        const float* wr = W_ih + gi * IDIM;
        float a0 = 0.f, a1 = 0.f;
        #pragma unroll
        for (int i = 0; i < IDIM; i += 4) {
            float4 wv = *(const float4*)&wr[i];
            float4 xv = *(const float4*)&xs[i];
            a0 += wv.x * xv.x + wv.z * xv.z;
            a1 += wv.y * xv.y + wv.w * xv.w;
        }
        const float scale = (gi >= 2 * HDIM && gi < 3 * HDIM) ? NEG_2L : NEG_L;
        xproj[(size_t)tb * GDIM + gi] = scale * (a0 + a1 + b_ih[gi] + b_hh[gi]);
    }
}

// K2 (merged): blocks 0..1 = serial LSTM; blocks 2.. = action dot-product
// in the LSTM's shadow. LSTM = r14 structure (permlane gate exchange,
// 2-step unroll) + r15 own/foreign broadcast split around a RAW s_barrier:
//   write h -> 6 OWN b128 reads (same-wave in-order DS, no barrier needed)
//   -> s_waitcnt lgkmcnt(6) (waits ONLY the write; own reads stay in flight)
//   -> raw s_barrier (no lgkmcnt(0) drain) -> 6 FOREIGN b128 reads.
// Own-half FMA (weights column-permuted own-first, r13-validated) then
// starts on data that completed under the barrier; foreign read latency
// hides under it.
__global__ __launch_bounds__(128)
__attribute__((amdgpu_waves_per_eu(1, 1)))
void lstm_action_kernel(
    const float* __restrict__ xproj,  // [T][B][176] (pre-scaled)
    const float* __restrict__ h0,     // [1][B][44]
    const float* __restrict__ c0,     // [1][B][44]
    const float* __restrict__ W_hh,   // [176][44]
    const float* __restrict__ W_v,    // [1][128]
    const float* __restrict__ b_v,    // [1]
    float* __restrict__ base_out,     // [B]
    const float* __restrict__ action, // [B][A][40]
    float* __restrict__ out)          // [B][A] (raw vals this pass)
{
    if (blockIdx.x >= BATCH) {
        // ---- action dot: out[idx] = action[idx,:]·w_a (mask/base later) ----
        const int idx = (blockIdx.x - BATCH) * 128 + threadIdx.x;
        const float* row = action + (size_t)idx * IDIM;
        float a0 = 0.f, a1 = 0.f;
        #pragma unroll
        for (int i = 0; i < IDIM; i += 4) {
            float4 av = *(const float4*)&row[i];
            a0 += av.x * W_v[EDIM + i + 0] + av.z * W_v[EDIM + i + 2];
            a1 += av.y * W_v[EDIM + i + 1] + av.w * W_v[EDIM + i + 3];
        }
        out[idx] = a0 + a1;
        return;
    }

    const int b    = blockIdx.x;
    const int tid  = threadIdx.x;      // 0..127
    const int wave = tid >> 6;         // 0,1
    const int lane = tid & 63;
    const int sub  = lane & 31;        // 0..21 active
    const int half = lane >> 5;        // 0: i,f   1: g,o
    const bool act = (sub < 22);
    const int subc = act ? sub : 21;   // clamped
    const int unit = wave * 22 + subc; // 0..43

    // double-buffered h: [buf][wave*32 + u], 16B-aligned blocks
    __shared__ __align__(16) float hsh[2][64];
    __shared__ float part[2];

    const int row0 = half ? (2 * HDIM + unit) : unit;          // g : i
    const int row1 = row0 + HDIM;                              // o : f
    const float sc0 = half ? NEG_2L : NEG_L;
    const float sc1 = NEG_L;

    const int ownb  = wave * 22;        // own column block (floats)
    const int forb  = (wave ^ 1) * 22;  // foreign column block
    const int wslot = wave * 32;        // own LDS slot base
    const int fbase = (wave ^ 1) * 32;  // foreign LDS slot base

    // weight pairs, column-permuted: own block first, then foreign
    v2f w0o[11], w0f[11], w1o[11], w1f[11];
    {
        const float* r0p = W_hh + (size_t)row0 * HDIM;
        const float* r1p = W_hh + (size_t)row1 * HDIM;
        #pragma unroll
        for (int k = 0; k < 11; ++k) {
            w0o[k] = ((const v2f*)(r0p + ownb))[k] * sc0;
            w0f[k] = ((const v2f*)(r0p + forb))[k] * sc0;
            w1o[k] = ((const v2f*)(r1p + ownb))[k] * sc1;
            w1f[k] = ((const v2f*)(r1p + forb))[k] * sc1;
        }
    }

    float c = c0[b * HDIM + unit];

    // initial h via LDS (both blocks), plain barrier once
    if (tid < HDIM) hsh[0][(tid / 22) * 32 + (tid % 22)] = h0[b * HDIM + tid];
    __syncthreads();
    v2f hO[11], hF[11];
    {
        const v4f* ob = (const v4f*)&hsh[0][wslot];
        const v4f* fb = (const v4f*)&hsh[0][fbase];
        #pragma unroll
        for (int k = 0; k < 11; ++k) {
            v4f oq = ob[k >> 1], fq = fb[k >> 1];
            hO[k] = (k & 1) ? __builtin_shufflevector(oq, oq, 2, 3)
                            : __builtin_shufflevector(oq, oq, 0, 1);
            hF[k] = (k & 1) ? __builtin_shufflevector(fq, fq, 2, 3)
                            : __builtin_shufflevector(fq, fq, 0, 1);
        }
    }
    __syncthreads();   // ensure init reads done before first overwrite of hsh[1]? (hsh[1] untouched; safe anyway)

    const float* xp = xproj + (size_t)b * GDIM;
    #define LDX(d0, d1, s) { const float* _a = xp + (size_t)(s) * (BATCH * GDIM); \
        d0 = _a[row0]; d1 = _a[row1]; }
    float r0v, r1v, p0v, p1v;
    LDX(r0v, r1v, 0) LDX(p0v, p1v, 1)

    float hval = 0.f;

    // one LSTM step; WB = static double-buffer index; NS = prefetch step
    #define STEP(WB, NS) { \
        /* own-half FMA first (data completed under previous barrier) */ \
        v2f a0 = {r0v, 0.f}, a1 = {r1v, 0.f}; \
        _Pragma("unroll") \
        for (int k = 0; k < 11; ++k) { \
            a0 = __builtin_elementwise_fma(w0o[k], hO[k], a0); \
            a1 = __builtin_elementwise_fma(w1o[k], hO[k], a1); \
        } \
        /* foreign-half FMA (latency hidden under own-half) */ \
        _Pragma("unroll") \
        for (int k = 0; k < 11; ++k) { \
            a0 = __builtin_elementwise_fma(w0f[k], hF[k], a0); \
            a1 = __builtin_elementwise_fma(w1f[k], hF[k], a1); \
        } \
        float y0 = a0.x + a0.y; \
        float y1 = a1.x + a1.y; \
        float v0 = __builtin_amdgcn_rcpf(1.0f + __builtin_amdgcn_exp2f(y0)); \
        float v1 = __builtin_amdgcn_rcpf(1.0f + __builtin_amdgcn_exp2f(y1)); \
        /* lane<->lane^32 exchange on the VALU (no DS pipe) */ \
        float sx1 = v0, sy1 = v1; \
        asm("v_permlane32_swap_b32 %0, %1" : "+v"(sx1), "+v"(sy1)); \
        float sx2 = v1, sy2 = v0; \
        asm("v_permlane32_swap_b32 %0, %1" : "+v"(sx2), "+v"(sy2)); \
        float s_i = half ? sx2 : v0; \
        float s_f = half ? sx1 : v1; \
        float w_g = half ? v0 : sy1; \
        float s_o = half ? v1 : sy2; \
        float t_g = __builtin_fmaf(2.0f, w_g, -1.0f); \
        c = s_f * c + s_i * t_g; \
        float w_c = __builtin_amdgcn_rcpf(1.0f + __builtin_amdgcn_exp2f(c * NEG_2L)); \
        hval = __builtin_fmaf(s_o + s_o, w_c, -s_o); \
        /* publish + OWN reads (same-wave in-order DS: no barrier needed) */ \
        hsh[WB][wslot + subc] = hval; \
        { \
            const v4f* ob = (const v4f*)&hsh[WB][wslot]; \
            _Pragma("unroll") \
            for (int k = 0; k < 11; ++k) { \
                v4f oq = ob[k >> 1]; \
                hO[k] = (k & 1) ? __builtin_shufflevector(oq, oq, 2, 3) \
                                : __builtin_shufflevector(oq, oq, 0, 1); \
            } \
        } \
        /* wait ONLY the write (6 own reads stay in flight), raw barrier */ \
        asm volatile("s_waitcnt lgkmcnt(6)" ::: "memory"); \
        __builtin_amdgcn_sched_barrier(0); \
        __builtin_amdgcn_s_barrier(); \
        __builtin_amdgcn_sched_barrier(0); \
        /* FOREIGN reads (visible after barrier; latency hides under next own-FMA) */ \
        { \
            const v4f* fb = (const v4f*)&hsh[WB][fbase]; \
            _Pragma("unroll") \
            for (int k = 0; k < 11; ++k) { \
                v4f fq = fb[k >> 1]; \
                hF[k] = (k & 1) ? __builtin_shufflevector(fq, fq, 2, 3) \
                                : __builtin_shufflevector(fq, fq, 0, 1); \
            } \
        } \
        r0v = p0v; r1v = p1v; \
        const int _ns = ((NS) < T_STEPS) ? (NS) : (T_STEPS - 1); \
        LDX(p0v, p1v, _ns) \
    }

    #pragma unroll 1
    for (int step = 0; step < T_STEPS; step += 2) {
        STEP(1, step + 2)
        STEP(0, step + 3)
    }
    #undef STEP
    #undef LDX

    // epilogue: base[b] = sum_u h[u]*Wv[u] + c[u]*Wv[44+u] + b_v
    float p = 0.f;
    if (act && half == 0) p = hval * W_v[unit] + c * W_v[HDIM + unit];
    #pragma unroll
    for (int off = 32; off; off >>= 1) p += __shfl_down(p, off);
    if (lane == 0) part[wave] = p;
    __syncthreads();
    if (tid == 0) base_out[b] = part[0] + part[1] + b_v[0];
}

// K3 (finalize): out[idx] = (a < len[b]) ? out[idx] + base[b] : 0
__global__ __launch_bounds__(256) void finalize_kernel(
    const int*   __restrict__ act_length, // [B]
    const float* __restrict__ base,       // [B]
    float* __restrict__ out)              // [B][A]
{
    const int idx = blockIdx.x * 256 + threadIdx.x;   // 0 .. B*A-1
    const int b = idx >> 18;                          // A = 2^18
    const int a = idx & (ADIM - 1);
    const float v = out[idx];
    out[idx] = (a < act_length[b]) ? v + base[b] : 0.f;
}

extern "C" void kernel_launch(void* const* d_in, const int* in_sizes, int n_in,
                              void* d_out, int out_size, void* d_ws, size_t ws_size,
                              hipStream_t stream) {
    const float* x        = (const float*)d_in[0];
    const float* h0       = (const float*)d_in[1];
    const float* c0       = (const float*)d_in[2];
    const float* action   = (const float*)d_in[3];
    const int*   act_len  = (const int*)  d_in[4];
    const float* W_ih     = (const float*)d_in[5];
    const float* W_hh     = (const float*)d_in[6];
    const float* b_ih     = (const float*)d_in[7];
    const float* b_hh     = (const float*)d_in[8];
    const float* W_v      = (const float*)d_in[9];
    const float* b_v      = (const float*)d_in[10];
    float* out = (float*)d_out;

    float* xproj = (float*)d_ws;                                   // [T][B][176]
    float* base  = xproj + (size_t)T_STEPS * BATCH * GDIM;         // B floats

    xproj_kernel<<<dim3(T_STEPS * BATCH), dim3(192), 0, stream>>>(
        x, W_ih, b_ih, b_hh, xproj);
    lstm_action_kernel<<<dim3(BATCH + NACT_BLK), dim3(128), 0, stream>>>(
        xproj, h0, c0, W_hh, W_v, b_v, base, action, out);
    finalize_kernel<<<dim3((BATCH * ADIM) / 256), dim3(256), 0, stream>>>(
        act_len, base, out);
}

// Round 17
// 564.748 us; speedup vs baseline: 1.0180x; 1.0180x over previous
//
#include <hip/hip_runtime.h>

typedef float v2f __attribute__((ext_vector_type(2)));
typedef float v4f __attribute__((ext_vector_type(4)));

#define T_STEPS 2048
#define BATCH   2
#define IDIM    40
#define HDIM    44
#define GDIM    176      // 4*H
#define ADIM    262144
#define EDIM    88       // 2*H
#define NEG_L   (-1.4426950408889634f)   // -log2(e)
#define NEG_2L  (-2.8853900817779268f)   // -2*log2(e)
#define NACT_BLK 4096                    // action blocks (128 thr each)

// K1: xproj[t][b][gi] = scale(gi) * (b_ih[gi] + b_hh[gi] + x[t][b]·W_ih[gi])
__global__ __launch_bounds__(192) void xproj_kernel(
    const float* __restrict__ x,      // [T][B][40]
    const float* __restrict__ W_ih,   // [176][40]
    const float* __restrict__ b_ih,   // [176]
    const float* __restrict__ b_hh,   // [176]
    float* __restrict__ xproj)        // [T][B][176]
{
    const int tb = blockIdx.x;        // t*B + b
    const int gi = threadIdx.x;
    __shared__ __align__(16) float xs[IDIM];
    if (threadIdx.x < IDIM) xs[threadIdx.x] = x[(size_t)tb * IDIM + threadIdx.x];
    __syncthreads();
    if (gi < GDIM) {
        const float* wr = W_ih + gi * IDIM;
        float a0 = 0.f, a1 = 0.f;
        #pragma unroll
        for (int i = 0; i < IDIM; i += 4) {
            float4 wv = *(const float4*)&wr[i];
            float4 xv = *(const float4*)&xs[i];
            a0 += wv.x * xv.x + wv.z * xv.z;
            a1 += wv.y * xv.y + wv.w * xv.w;
        }
        const float scale = (gi >= 2 * HDIM && gi < 3 * HDIM) ? NEG_2L : NEG_L;
        xproj[(size_t)tb * GDIM + gi] = scale * (a0 + a1 + b_ih[gi] + b_hh[gi]);
    }
}

// K2 (merged): blocks 0..1 = serial LSTM (r12 structure, permlane32_swap
// gate exchange + 2-step unroll); blocks 2.. = action dot-product (raw vals,
// no mask/base) running on otherwise-idle CUs in the LSTM's shadow.
// This is the measured optimum (r14, 565 µs): every structural alternative
// (bpermute/readlane broadcast, raw-barrier own/foreign split, transposed
// streams, deeper prefetch, 1/merged/3-wave layouts) benched worse or null.
__global__ __launch_bounds__(128)
__attribute__((amdgpu_waves_per_eu(1, 1)))
void lstm_action_kernel(
    const float* __restrict__ xproj,  // [T][B][176] (pre-scaled)
    const float* __restrict__ h0,     // [1][B][44]
    const float* __restrict__ c0,     // [1][B][44]
    const float* __restrict__ W_hh,   // [176][44]
    const float* __restrict__ W_v,    // [1][128]
    const float* __restrict__ b_v,    // [1]
    float* __restrict__ base_out,     // [B]
    const float* __restrict__ action, // [B][A][40]
    float* __restrict__ out)          // [B][A] (raw vals this pass)
{
    if (blockIdx.x >= BATCH) {
        // ---- action dot: out[idx] = action[idx,:]·w_a (mask/base later) ----
        const int idx = (blockIdx.x - BATCH) * 128 + threadIdx.x;
        const float* row = action + (size_t)idx * IDIM;
        float a0 = 0.f, a1 = 0.f;
        #pragma unroll
        for (int i = 0; i < IDIM; i += 4) {
            float4 av = *(const float4*)&row[i];
            a0 += av.x * W_v[EDIM + i + 0] + av.z * W_v[EDIM + i + 2];
            a1 += av.y * W_v[EDIM + i + 1] + av.w * W_v[EDIM + i + 3];
        }
        out[idx] = a0 + a1;
        return;
    }

    const int b    = blockIdx.x;
    const int tid  = threadIdx.x;      // 0..127
    const int wave = tid >> 6;         // 0,1
    const int lane = tid & 63;
    const int sub  = lane & 31;        // 0..21 active
    const int half = lane >> 5;        // 0: i,f   1: g,o
    const bool act = (sub < 22);
    const int subc = act ? sub : 21;   // clamped
    const int unit = wave * 22 + subc; // 0..43

    __shared__ __align__(16) float hsh[2][64];
    __shared__ float part[2];

    const int row0 = half ? (2 * HDIM + unit) : unit;          // g : i
    const int row1 = row0 + HDIM;                              // o : f
    const float sc0 = half ? NEG_2L : NEG_L;
    const float sc1 = NEG_L;

    v2f w0[22], w1[22];
    {
        const float* r0p = W_hh + (size_t)row0 * HDIM;
        const float* r1p = W_hh + (size_t)row1 * HDIM;
        #pragma unroll
        for (int k = 0; k < 22; ++k) {
            w0[k] = ((const v2f*)r0p)[k] * sc0;
            w1[k] = ((const v2f*)r1p)[k] * sc1;
        }
    }

    float c = c0[b * HDIM + unit];
    if (tid < HDIM) hsh[0][tid] = h0[b * HDIM + tid];
    if (tid >= HDIM && tid < 64) hsh[0][tid] = 0.f;
    __syncthreads();

    v2f hp[22];
    #pragma unroll
    for (int k = 0; k < 11; ++k) {
        v4f t = ((const v4f*)hsh[0])[k];
        hp[2 * k]     = __builtin_shufflevector(t, t, 0, 1);
        hp[2 * k + 1] = __builtin_shufflevector(t, t, 2, 3);
    }

    const float* xp = xproj + (size_t)b * GDIM;
    #define LDX(d0, d1, s) { const float* _a = xp + (size_t)(s) * (BATCH * GDIM); \
        d0 = _a[row0]; d1 = _a[row1]; }
    float r0v, r1v, p0v, p1v;
    LDX(r0v, r1v, 0) LDX(p0v, p1v, 1)

    float hval = 0.f;

    // one LSTM step; WB = static double-buffer index; NS = prefetch step
    #define STEP(WB, NS) { \
        v2f a0 = {r0v, 0.f}, a1 = {r1v, 0.f}; \
        _Pragma("unroll") \
        for (int k = 0; k < 22; ++k) { \
            a0 = __builtin_elementwise_fma(w0[k], hp[k], a0); \
            a1 = __builtin_elementwise_fma(w1[k], hp[k], a1); \
        } \
        float y0 = a0.x + a0.y; \
        float y1 = a1.x + a1.y; \
        float v0 = __builtin_amdgcn_rcpf(1.0f + __builtin_amdgcn_exp2f(y0)); \
        float v1 = __builtin_amdgcn_rcpf(1.0f + __builtin_amdgcn_exp2f(y1)); \
        /* lane<->lane^32 exchange on the VALU (no DS pipe): */ \
        /* swap1(X=v0,Y=v1): low lanes' Y = o0; high lanes' X = o1 */ \
        float sx1 = v0, sy1 = v1; \
        asm("v_permlane32_swap_b32 %0, %1" : "+v"(sx1), "+v"(sy1)); \
        float sx2 = v1, sy2 = v0; \
        asm("v_permlane32_swap_b32 %0, %1" : "+v"(sx2), "+v"(sy2)); \
        float s_i = half ? sx2 : v0; \
        float s_f = half ? sx1 : v1; \
        float w_g = half ? v0 : sy1; \
        float s_o = half ? v1 : sy2; \
        float t_g = __builtin_fmaf(2.0f, w_g, -1.0f); \
        c = s_f * c + s_i * t_g; \
        float w_c = __builtin_amdgcn_rcpf(1.0f + __builtin_amdgcn_exp2f(c * NEG_2L)); \
        hval = __builtin_fmaf(s_o + s_o, w_c, -s_o); \
        hsh[WB][unit] = hval; \
        __syncthreads(); \
        _Pragma("unroll") \
        for (int k = 0; k < 11; ++k) { \
            v4f t = ((const v4f*)hsh[WB])[k]; \
            hp[2 * k]     = __builtin_shufflevector(t, t, 0, 1); \
            hp[2 * k + 1] = __builtin_shufflevector(t, t, 2, 3); \
        } \
        r0v = p0v; r1v = p1v; \
        const int _ns = ((NS) < T_STEPS) ? (NS) : (T_STEPS - 1); \
        LDX(p0v, p1v, _ns) \
    }

    #pragma unroll 1
    for (int step = 0; step < T_STEPS; step += 2) {
        STEP(1, step + 2)
        STEP(0, step + 3)
    }
    #undef STEP
    #undef LDX

    // epilogue: base[b] = sum_u h[u]*Wv[u] + c[u]*Wv[44+u] + b_v
    float p = 0.f;
    if (act && half == 0) p = hval * W_v[unit] + c * W_v[HDIM + unit];
    #pragma unroll
    for (int off = 32; off; off >>= 1) p += __shfl_down(p, off);
    if (lane == 0) part[wave] = p;
    __syncthreads();
    if (tid == 0) base_out[b] = part[0] + part[1] + b_v[0];
}

// K3 (finalize): out[idx] = (a < len[b]) ? out[idx] + base[b] : 0
__global__ __launch_bounds__(256) void finalize_kernel(
    const int*   __restrict__ act_length, // [B]
    const float* __restrict__ base,       // [B]
    float* __restrict__ out)              // [B][A]
{
    const int idx = blockIdx.x * 256 + threadIdx.x;   // 0 .. B*A-1
    const int b = idx >> 18;                          // A = 2^18
    const int a = idx & (ADIM - 1);
    const float v = out[idx];
    out[idx] = (a < act_length[b]) ? v + base[b] : 0.f;
}

extern "C" void kernel_launch(void* const* d_in, const int* in_sizes, int n_in,
                              void* d_out, int out_size, void* d_ws, size_t ws_size,
                              hipStream_t stream) {
    const float* x        = (const float*)d_in[0];
    const float* h0       = (const float*)d_in[1];
    const float* c0       = (const float*)d_in[2];
    const float* action   = (const float*)d_in[3];
    const int*   act_len  = (const int*)  d_in[4];
    const float* W_ih     = (const float*)d_in[5];
    const float* W_hh     = (const float*)d_in[6];
    const float* b_ih     = (const float*)d_in[7];
    const float* b_hh     = (const float*)d_in[8];
    const float* W_v      = (const float*)d_in[9];
    const float* b_v      = (const float*)d_in[10];
    float* out = (float*)d_out;

    float* xproj = (float*)d_ws;                                   // [T][B][176]
    float* base  = xproj + (size_t)T_STEPS * BATCH * GDIM;         // B floats

    xproj_kernel<<<dim3(T_STEPS * BATCH), dim3(192), 0, stream>>>(
        x, W_ih, b_ih, b_hh, xproj);
    lstm_action_kernel<<<dim3(BATCH + NACT_BLK), dim3(128), 0, stream>>>(
        xproj, h0, c0, W_hh, W_v, b_v, base, action, out);
    finalize_kernel<<<dim3((BATCH * ADIM) / 256), dim3(256), 0, stream>>>(
        act_len, base, out);
}